// Round 15
// baseline (323.298 us; speedup 1.0000x reference)
//
#include <hip/hip_runtime.h>

#define NB 128
#define NT 512
#define NL 256
#define NWG NB           // one workgroup per batch

typedef float f32x4 __attribute__((ext_vector_type(4)));
typedef int   i32x8 __attribute__((ext_vector_type(8)));

#define EASTRIDE 272     // bytes per EA buffer (256 + 16 pad, 16B aligned)
#define GEXP 7           // a-priori per-step log2 growth estimate
#define E8M0_ONE 127     // e8m0 encoding of 1.0 for mfma_scale
#define INV_LN2 1.4426950408889634f
#define LN2 0.6931471805599453f

__device__ inline float log2_fast(float x) {
#if __has_builtin(__builtin_amdgcn_logf)
    return __builtin_amdgcn_logf(x);
#else
    return __log2f(x);
#endif
}
__device__ inline float exp2_fast(float x) {
#if __has_builtin(__builtin_amdgcn_exp2f)
    return __builtin_amdgcn_exp2f(x);
#else
    return exp2f(x);
#endif
}

// Barrier that waits only on LDS/SMEM ops — prefetch global loads stay in flight.
__device__ inline void barrier_lds_only() {
    asm volatile("s_waitcnt lgkmcnt(0)" ::: "memory");
    __builtin_amdgcn_s_barrier();
    asm volatile("" ::: "memory");
}

// pack 4 f32 -> 4 fp8 e4m3 bytes (saturating)
__device__ inline unsigned pk_fp8x4(float a, float b, float c, float d) {
    int w = __builtin_amdgcn_cvt_pk_fp8_f32(a, b, 0, false);
    w     = __builtin_amdgcn_cvt_pk_fp8_f32(c, d, w, true);
    return (unsigned)w;
}

// One WG (512 thr = 8 waves, 2 waves/SIMD) per batch.  Same verified numerics
// family as r8-r14 (absmax 0.0 x6): exp-space recurrence, power-of-2
// normalization, S accumulates exact integer exponents.  r14 post-mortem:
// step = per-CU DS-pipe serialization + chain tail.  Changes:
//  * LAG-2 DEFERRED MAX: step t keeps only a lane-local fmax tree; the
//    cross-lane shuffles + pm write run early in step t+1 (overlapped under
//    ds_read/MFMA wait).  kb_t = floor(log2 gmax(EA_{t-2})) + 2*GEXP - kb_{t-1}
//    => E_t = frac(E_{t-2}) + d_{t-1} + d_t  (contraction, no unit root).
//  * PERMUTED EA: row r stored at k = wv*32+g*8+T*4+reg -> each wave writes
//    8 contiguous bytes = one ds_write_b64.  A-frag columns permuted to match
//    (float4 col offsets {0,16,4,20,8,24,12,28}); final sum perm-invariant.
//  * s_load of next word hoisted to step top.
// Layout (16x16x128): A row=lane&15, k=(lane>>4)*32+j; B col=lane&15 (batch
// dup), same k; D col=lane&15, row=g*4+reg.
__global__ __launch_bounds__(512, 2) void crf_forward(
    const float* __restrict__ emis,
    const float* __restrict__ trans,
    const int*   __restrict__ words,
    float*       __restrict__ bout)
{
    const int tid = threadIdx.x;
    const int l   = tid & 63;
    const int wv  = tid >> 6;    // 0..7
    const int g   = l >> 4;      // 0..3
    const int b   = l & 15;

    __shared__ __align__(16) unsigned char ea[2][EASTRIDE]; // fp8 EA, dbuf
    __shared__ __align__(16) float pm[2][8];                // per-wave maxes, lag ring

    const int* ws = words + (size_t)blockIdx.x * NT;  // uniform base -> s_load
    const int eoff = wv * 32 + g * 4;                 // lane offset into emis row

    // ---- A-fragments: exp(trans) rows wv*32 + T*16 + b; columns permuted ----
    static const int coff[8] = {0, 16, 4, 20, 8, 24, 12, 28};
    i32x8 afr[2][2];
    #pragma unroll
    for (int T = 0; T < 2; ++T) {
        const int row = wv * 32 + T * 16 + b;
        #pragma unroll
        for (int kt = 0; kt < 2; ++kt) {
            const float* src = trans + row * NL + (kt * 4 + g) * 32;
            i32x8 a;
            #pragma unroll
            for (int jj = 0; jj < 8; ++jj) {
                float4 v = *reinterpret_cast<const float4*>(src + coff[jj]);
                a[jj] = (int)pk_fp8x4(__expf(v.x), __expf(v.y),
                                      __expf(v.z), __expf(v.w));
            }
            afr[T][kt] = a;
        }
    }

    // ---- word pipeline: 2-deep emission prefetch, scalar indices ----
    const int w0 = ws[0];
    const int w1 = ws[1];
    const int w2 = ws[2];
    int wA = ws[3];
    int wB = ws[4];

    float S = 0.f;     // exponent accumulator (exact small ints)
    int   kbp = GEXP;  // kb_{t-1}
    float mprev;       // lane-local max of EA_{t-1} (deferred reduce)

    // ---- t=0 : EA_0 = fp8(2^(e0*INV_LN2)); exact gmax into both pm slots ----
    {
        const float* e0 = emis + (size_t)w0 * NL + eoff;
        f32x4 v0 = *reinterpret_cast<const f32x4*>(e0);
        f32x4 v1 = *reinterpret_cast<const f32x4*>(e0 + 16);
        float p00 = exp2_fast(v0[0] * INV_LN2), p01 = exp2_fast(v0[1] * INV_LN2);
        float p02 = exp2_fast(v0[2] * INV_LN2), p03 = exp2_fast(v0[3] * INV_LN2);
        float p10 = exp2_fast(v1[0] * INV_LN2), p11 = exp2_fast(v1[1] * INV_LN2);
        float p12 = exp2_fast(v1[2] * INV_LN2), p13 = exp2_fast(v1[3] * INV_LN2);
        mprev = fmaxf(fmaxf(fmaxf(p00, p01), fmaxf(p02, p03)),
                      fmaxf(fmaxf(p10, p11), fmaxf(p12, p13)));
        float gmax = fmaxf(mprev, __shfl_xor(mprev, 16));
        gmax = fmaxf(gmax, __shfl_xor(gmax, 32));
        if (l == 0) { pm[0][wv] = gmax; pm[1][wv] = gmax; }
        if (b == 0) {
            unsigned q0 = pk_fp8x4(p00, p01, p02, p03);
            unsigned q1 = pk_fp8x4(p10, p11, p12, p13);
            *reinterpret_cast<unsigned long long*>(&ea[0][wv * 32 + g * 8]) =
                ((unsigned long long)q1 << 32) | q0;
        }
    }
    f32x4 pfA0, pfA1, pfB0, pfB1;
    {
        const float* p1 = emis + (size_t)w1 * NL + eoff;
        pfA0 = *reinterpret_cast<const f32x4*>(p1);
        pfA1 = *reinterpret_cast<const f32x4*>(p1 + 16);
        const float* p2 = emis + (size_t)w2 * NL + eoff;
        pfB0 = *reinterpret_cast<const f32x4*>(p2);
        pfB1 = *reinterpret_cast<const f32x4*>(p2 + 16);
    }
    barrier_lds_only();

#define CRF_STEP(t, EARD, EAWR, PMRD, PMWR, PF0, PF1, WREG)                     \
    {                                                                           \
        /* hoisted next-word scalar load (drains during the step) */            \
        int wnext = 0;                                                          \
        if ((t) + 4 < NT) wnext = ws[(t) + 4];                                  \
        /* B-frags + stale (lag-2) pm read */                                   \
        i32x8 bq0 = *reinterpret_cast<const i32x8*>(&ea[EARD][0]);              \
        i32x8 bq1 = *reinterpret_cast<const i32x8*>(&ea[EARD][128]);            \
        f32x4 pm0 = *reinterpret_cast<const f32x4*>(&pm[PMRD][0]);              \
        f32x4 pm1 = *reinterpret_cast<const f32x4*>(&pm[PMRD][4]);              \
        /* deferred reduce of EA_{t-1} local max (off-chain, overlaps MFMA) */  \
        float m1 = fmaxf(mprev, __shfl_xor(mprev, 16));                         \
        m1 = fmaxf(m1, __shfl_xor(m1, 32));                                     \
        if (l == 0) pm[PMWR][wv] = m1;                                          \
        float gm = fmaxf(fmaxf(fmaxf(pm0[0], pm0[1]), fmaxf(pm0[2], pm0[3])),   \
                         fmaxf(fmaxf(pm1[0], pm1[1]), fmaxf(pm1[2], pm1[3])));  \
        int kb = ((int)(__builtin_bit_cast(unsigned, gm) >> 23) - 127)          \
                 + 2 * GEXP - kbp;                                              \
        kbp = kb;                                                               \
        S += (float)kb;                                                         \
        float kbf = (float)kb;                                                  \
        /* ex from current PF regs, then reload PF */                           \
        float exa0 = exp2_fast(fmaf(PF0[0], INV_LN2, -kbf));                    \
        float exa1 = exp2_fast(fmaf(PF0[1], INV_LN2, -kbf));                    \
        float exa2 = exp2_fast(fmaf(PF0[2], INV_LN2, -kbf));                    \
        float exa3 = exp2_fast(fmaf(PF0[3], INV_LN2, -kbf));                    \
        float exb0 = exp2_fast(fmaf(PF1[0], INV_LN2, -kbf));                    \
        float exb1 = exp2_fast(fmaf(PF1[1], INV_LN2, -kbf));                    \
        float exb2 = exp2_fast(fmaf(PF1[2], INV_LN2, -kbf));                    \
        float exb3 = exp2_fast(fmaf(PF1[3], INV_LN2, -kbf));                    \
        if ((t) + 2 < NT) {                                                     \
            const float* ep = emis + (size_t)WREG * NL + eoff;                  \
            PF0 = *reinterpret_cast<const f32x4*>(ep);                          \
            PF1 = *reinterpret_cast<const f32x4*>(ep + 16);                     \
        }                                                                       \
        WREG = wnext;                                                           \
        /* 2 parallel depth-2 scale-MFMA chains (K=128 each) */                 \
        f32x4 z0 = {0.f, 0.f, 0.f, 0.f};                                        \
        f32x4 z1 = {0.f, 0.f, 0.f, 0.f};                                        \
        z0 = __builtin_amdgcn_mfma_scale_f32_16x16x128_f8f6f4(                  \
                 afr[0][0], bq0, z0, 0, 0, 0, E8M0_ONE, 0, E8M0_ONE);           \
        z1 = __builtin_amdgcn_mfma_scale_f32_16x16x128_f8f6f4(                  \
                 afr[1][0], bq0, z1, 0, 0, 0, E8M0_ONE, 0, E8M0_ONE);           \
        z0 = __builtin_amdgcn_mfma_scale_f32_16x16x128_f8f6f4(                  \
                 afr[0][1], bq1, z0, 0, 0, 0, E8M0_ONE, 0, E8M0_ONE);           \
        z1 = __builtin_amdgcn_mfma_scale_f32_16x16x128_f8f6f4(                  \
                 afr[1][1], bq1, z1, 0, 0, 0, E8M0_ONE, 0, E8M0_ONE);           \
        float v00 = fminf(z0[0] * exa0, 440.f), v01 = fminf(z0[1] * exa1, 440.f);\
        float v02 = fminf(z0[2] * exa2, 440.f), v03 = fminf(z0[3] * exa3, 440.f);\
        float v10 = fminf(z1[0] * exb0, 440.f), v11 = fminf(z1[1] * exb1, 440.f);\
        float v12 = fminf(z1[2] * exb2, 440.f), v13 = fminf(z1[3] * exb3, 440.f);\
        if (b == 0) {                                                           \
            unsigned q0 = pk_fp8x4(v00, v01, v02, v03);                         \
            unsigned q1 = pk_fp8x4(v10, v11, v12, v13);                         \
            *reinterpret_cast<unsigned long long*>(                             \
                &ea[EAWR][wv * 32 + g * 8]) =                                   \
                ((unsigned long long)q1 << 32) | q0;                            \
        }                                                                       \
        /* lane-local max only; cross-lane reduce deferred to next step */      \
        mprev = fmaxf(fmaxf(fmaxf(v00, v01), fmaxf(v02, v03)),                  \
                      fmaxf(fmaxf(v10, v11), fmaxf(v12, v13)));                 \
        barrier_lds_only();                                                     \
    }

    for (int t = 1; t + 1 < NT; t += 2) {
        CRF_STEP(t,     0, 1, 1, 0, pfA0, pfA1, wA);   // odd t
        CRF_STEP(t + 1, 1, 0, 0, 1, pfB0, pfB1, wB);   // even t
    }
    CRF_STEP(511, 0, 1, 1, 0, pfA0, pfA1, wA);   // final EA lands in ea[1]
#undef CRF_STEP

    // ---- final: logZ_b = ln2 * (S + log2(sum_k EA_last[k])) ----
    if (tid < 64) {
        unsigned u = *reinterpret_cast<const unsigned*>(&ea[1][tid * 4]);
        float s = __builtin_amdgcn_cvt_f32_fp8((int)u, 0)
                + __builtin_amdgcn_cvt_f32_fp8((int)u, 1)
                + __builtin_amdgcn_cvt_f32_fp8((int)u, 2)
                + __builtin_amdgcn_cvt_f32_fp8((int)u, 3);
        #pragma unroll
        for (int off = 32; off; off >>= 1) s += __shfl_xor(s, off);
        if (tid == 0) bout[blockIdx.x] = (S + log2_fast(s)) * LN2;
    }
}

__global__ void crf_reduce(const float* __restrict__ bout, float* __restrict__ out)
{
    const int tid = threadIdx.x;  // 128 threads
    float v = bout[tid];
    #pragma unroll
    for (int off = 32; off; off >>= 1) v += __shfl_xor(v, off);
    __shared__ float sred[2];
    if ((tid & 63) == 0) sred[tid >> 6] = v;
    __syncthreads();
    if (tid == 0) out[0] = sred[0] + sred[1];
}

extern "C" void kernel_launch(void* const* d_in, const int* in_sizes, int n_in,
                              void* d_out, int out_size, void* d_ws, size_t ws_size,
                              hipStream_t stream)
{
    const float* emis  = (const float*)d_in[0];
    const float* trans = (const float*)d_in[1];
    const int*   words = (const int*)d_in[2];
    float* out  = (float*)d_out;
    float* bout = (float*)d_ws;   // NWG floats of scratch

    crf_forward<<<NWG, 512, 0, stream>>>(emis, trans, words, bout);
    crf_reduce<<<1, NB, 0, stream>>>(bout, out);
}

// Round 16
// 308.805 us; speedup vs baseline: 1.0469x; 1.0469x over previous
//
#include <hip/hip_runtime.h>

#define NB 128
#define NT 512
#define NL 256
#define NWG NB           // one workgroup per batch

typedef float f32x4 __attribute__((ext_vector_type(4)));
typedef int   i32x8 __attribute__((ext_vector_type(8)));

#define EASTRIDE 272     // bytes per EA buffer (256 + 16 pad, 16B aligned)
#define GEXP 7           // a-priori per-step log2 growth estimate
#define E8M0_ONE 127     // e8m0 encoding of 1.0 for mfma_scale
#define INV_LN2 1.4426950408889634f
#define LN2 0.6931471805599453f

__device__ inline float log2_fast(float x) {
#if __has_builtin(__builtin_amdgcn_logf)
    return __builtin_amdgcn_logf(x);
#else
    return __log2f(x);
#endif
}
__device__ inline float exp2_fast(float x) {
#if __has_builtin(__builtin_amdgcn_exp2f)
    return __builtin_amdgcn_exp2f(x);
#else
    return exp2f(x);
#endif
}

// Barrier that waits only on LDS/SMEM ops — prefetch global loads stay in flight.
__device__ inline void barrier_lds_only() {
    asm volatile("s_waitcnt lgkmcnt(0)" ::: "memory");
    __builtin_amdgcn_s_barrier();
    asm volatile("" ::: "memory");
}

// pack 4 f32 -> 4 fp8 e4m3 bytes (saturating)
__device__ inline unsigned pk_fp8x4(float a, float b, float c, float d) {
    int w = __builtin_amdgcn_cvt_pk_fp8_f32(a, b, 0, false);
    w     = __builtin_amdgcn_cvt_pk_fp8_f32(c, d, w, true);
    return (unsigned)w;
}

__device__ inline f32x4 vmax4(f32x4 a, f32x4 b) {
    f32x4 r;
    r[0] = fmaxf(a[0], b[0]); r[1] = fmaxf(a[1], b[1]);
    r[2] = fmaxf(a[2], b[2]); r[3] = fmaxf(a[3], b[3]);
    return r;
}

// One WG (512 thr = 8 waves, 2 waves/SIMD) per batch.  Value stream identical
// to r13 (293us, passed): exp-space recurrence, damped power-of-2
// normalization from a one-step-stale max, S accumulates exact integers.
// r16 chain cuts (everything else r13-verbatim):
//  * INDEPENDENT MFMA ACCUMULATORS: the two K=128 halves accumulate into
//    separate registers, summed by a vector add -> dep chain 2L -> L+8cy.
//  * ONE-SHUFFLE MAX REDUCE: lane-local max is b-invariant (batch-dup cols);
//    one shfl_xor(16) + two writer lanes (l==0, l==32) -> pm has 16 partials;
//    the wider consumer tree hides under the MFMA wait.
// Layout (16x16x128): A row=lane&15, k=(lane>>4)*32+j; B col=lane&15 (batch
// dup), same k; D col=lane&15, row=g*4+reg.
__global__ __launch_bounds__(512, 2) void crf_forward(
    const float* __restrict__ emis,
    const float* __restrict__ trans,
    const int*   __restrict__ words,
    float*       __restrict__ bout)
{
    const int tid = threadIdx.x;
    const int l   = tid & 63;
    const int wv  = tid >> 6;    // 0..7
    const int g   = l >> 4;      // 0..3
    const int b   = l & 15;

    __shared__ __align__(16) unsigned char ea[2][EASTRIDE]; // fp8 EA, dbuf
    __shared__ __align__(16) float pm[2][16];               // per-(wave,half) maxes
    __shared__ int wlds[NT];                                // staged word indices

    const int wrow = blockIdx.x * NT;

    // ---- stage word indices to LDS ----
    wlds[tid] = words[wrow + tid];

    // ---- A-fragments: exp(trans) rows wv*32 + T*16 + b, K=128 layout ----
    i32x8 afr[2][2];
    #pragma unroll
    for (int T = 0; T < 2; ++T) {
        const int row = wv * 32 + T * 16 + b;
        #pragma unroll
        for (int kt = 0; kt < 2; ++kt) {
            const float* src = trans + row * NL + kt * 128 + g * 32;
            i32x8 a;
            #pragma unroll
            for (int w = 0; w < 8; ++w) {
                float4 v = *reinterpret_cast<const float4*>(src + w * 4);
                a[w] = (int)pk_fp8x4(__expf(v.x), __expf(v.y),
                                     __expf(v.z), __expf(v.w));
            }
            afr[T][kt] = a;
        }
    }

    // ---- word pipeline (prologue direct; steady: wlds ds_read) ----
    const int w0 = words[wrow + 0];
    const int w1 = words[wrow + 1];
    const int w2 = words[wrow + 2];
    const int w3 = words[wrow + 3];
    const int w4 = words[wrow + 4];
    int wregA = words[wrow + 5];
    int wregB = words[wrow + 6];
    int wregC = words[wrow + 7];
    int wregD = words[wrow + 8];

    float S = 0.f;   // exponent accumulator (exact small ints, same in all lanes)

    // ---- t=0 : EA_0 = fp8(2^(e0*INV_LN2)), rows wv*32 + T*16 + g*4 + j ----
    {
        const float* e0 = emis + (size_t)w0 * NL + wv * 32 + g * 4;
        float pmax = 0.f;
        unsigned pk[2];
        #pragma unroll
        for (int T = 0; T < 2; ++T) {
            f32x4 v = *reinterpret_cast<const f32x4*>(e0 + T * 16);
            float p0 = exp2_fast(v[0] * INV_LN2);
            float p1 = exp2_fast(v[1] * INV_LN2);
            float p2 = exp2_fast(v[2] * INV_LN2);
            float p3 = exp2_fast(v[3] * INV_LN2);
            pmax = fmaxf(pmax, fmaxf(fmaxf(p0, p1), fmaxf(p2, p3)));
            pk[T] = pk_fp8x4(p0, p1, p2, p3);
        }
        pmax = fmaxf(pmax, __shfl_xor(pmax, 16));
        if ((l & 31) == 0) pm[0][wv * 2 + (l >> 5)] = pmax;
        if (b == 0) {
            *reinterpret_cast<unsigned*>(&ea[0][wv * 32 + g * 4])      = pk[0];
            *reinterpret_cast<unsigned*>(&ea[0][wv * 32 + 16 + g * 4]) = pk[1];
        }
    }
    f32x4 pfA[2], pfB[2], pfC[2], pfD[2];
    {
        const float* p;
        p = emis + (size_t)w1 * NL + wv * 32 + g * 4;
        pfA[0] = *(const f32x4*)p; pfA[1] = *(const f32x4*)(p + 16);
        p = emis + (size_t)w2 * NL + wv * 32 + g * 4;
        pfB[0] = *(const f32x4*)p; pfB[1] = *(const f32x4*)(p + 16);
        p = emis + (size_t)w3 * NL + wv * 32 + g * 4;
        pfC[0] = *(const f32x4*)p; pfC[1] = *(const f32x4*)(p + 16);
        p = emis + (size_t)w4 * NL + wv * 32 + g * 4;
        pfD[0] = *(const f32x4*)p; pfD[1] = *(const f32x4*)(p + 16);
    }
    barrier_lds_only();

#define CRF_STEP(t, RD, WR, PF, WREG)                                           \
    {                                                                           \
        /* B-frags + stale pm: all LDS reads issued together */                 \
        i32x8 bq0 = *reinterpret_cast<const i32x8*>(&ea[RD][g * 32]);           \
        i32x8 bq1 = *reinterpret_cast<const i32x8*>(&ea[RD][128 + g * 32]);     \
        f32x4 pm0 = *reinterpret_cast<const f32x4*>(&pm[RD][0]);                \
        f32x4 pm1 = *reinterpret_cast<const f32x4*>(&pm[RD][4]);                \
        f32x4 pm2 = *reinterpret_cast<const f32x4*>(&pm[RD][8]);                \
        f32x4 pm3 = *reinterpret_cast<const f32x4*>(&pm[RD][12]);               \
        f32x4 mm  = vmax4(vmax4(pm0, pm1), vmax4(pm2, pm3));                    \
        float gm  = fmaxf(fmaxf(mm[0], mm[1]), fmaxf(mm[2], mm[3]));            \
        int   kb  = (int)(__builtin_bit_cast(unsigned, gm) >> 23) - (127 - GEXP);\
        S += (float)kb;                                                         \
        float kbf = (float)kb;                                                  \
        f32x4 eC[2] = { PF[0], PF[1] };                                         \
        if ((t) + 4 < NT) {                                                     \
            const float* ep = emis + (size_t)WREG * NL + wv * 32 + g * 4;       \
            PF[0] = *(const f32x4*)ep;  PF[1] = *(const f32x4*)(ep + 16);       \
        }                                                                       \
        if ((t) + 8 < NT) WREG = wlds[(t) + 8];                                 \
        /* ex hides under lgkm/MFMA wait */                                     \
        f32x4 ex[2];                                                            \
        _Pragma("unroll")                                                       \
        for (int T = 0; T < 2; ++T) {                                           \
            ex[T][0] = exp2_fast(fmaf(eC[T][0], INV_LN2, -kbf));                \
            ex[T][1] = exp2_fast(fmaf(eC[T][1], INV_LN2, -kbf));                \
            ex[T][2] = exp2_fast(fmaf(eC[T][2], INV_LN2, -kbf));                \
            ex[T][3] = exp2_fast(fmaf(eC[T][3], INV_LN2, -kbf));                \
        }                                                                       \
        /* 4 fully independent K=128 scale-MFMAs (chain depth 1) */             \
        f32x4 z0a = {0.f,0.f,0.f,0.f}, z0b = {0.f,0.f,0.f,0.f};                 \
        f32x4 z1a = {0.f,0.f,0.f,0.f}, z1b = {0.f,0.f,0.f,0.f};                 \
        z0a = __builtin_amdgcn_mfma_scale_f32_16x16x128_f8f6f4(                 \
                  afr[0][0], bq0, z0a, 0, 0, 0, E8M0_ONE, 0, E8M0_ONE);         \
        z1a = __builtin_amdgcn_mfma_scale_f32_16x16x128_f8f6f4(                 \
                  afr[1][0], bq0, z1a, 0, 0, 0, E8M0_ONE, 0, E8M0_ONE);         \
        z0b = __builtin_amdgcn_mfma_scale_f32_16x16x128_f8f6f4(                 \
                  afr[0][1], bq1, z0b, 0, 0, 0, E8M0_ONE, 0, E8M0_ONE);         \
        z1b = __builtin_amdgcn_mfma_scale_f32_16x16x128_f8f6f4(                 \
                  afr[1][1], bq1, z1b, 0, 0, 0, E8M0_ONE, 0, E8M0_ONE);         \
        f32x4 z0 = z0a + z0b;                                                   \
        f32x4 z1 = z1a + z1b;                                                   \
        float v00 = z0[0] * ex[0][0], v01 = z0[1] * ex[0][1];                   \
        float v02 = z0[2] * ex[0][2], v03 = z0[3] * ex[0][3];                   \
        float v10 = z1[0] * ex[1][0], v11 = z1[1] * ex[1][1];                   \
        float v12 = z1[2] * ex[1][2], v13 = z1[3] * ex[1][3];                   \
        /* EA write first (frees the barrier), max reduce after */              \
        if (b == 0) {                                                           \
            *reinterpret_cast<unsigned*>(&ea[WR][wv * 32 + g * 4]) =            \
                pk_fp8x4(v00, v01, v02, v03);                                   \
            *reinterpret_cast<unsigned*>(&ea[WR][wv * 32 + 16 + g * 4]) =       \
                pk_fp8x4(v10, v11, v12, v13);                                   \
        }                                                                       \
        float pmax = fmaxf(fmaxf(fmaxf(v00, v01), fmaxf(v02, v03)),             \
                           fmaxf(fmaxf(v10, v11), fmaxf(v12, v13)));            \
        pmax = fmaxf(pmax, __shfl_xor(pmax, 16));                               \
        if ((l & 31) == 0) pm[WR][wv * 2 + (l >> 5)] = pmax;                    \
        barrier_lds_only();                                                     \
    }

    int t = 1;
    for (; t + 3 < NT; t += 4) {
        CRF_STEP(t,     0, 1, pfA, wregA);
        CRF_STEP(t + 1, 1, 0, pfB, wregB);
        CRF_STEP(t + 2, 0, 1, pfC, wregC);
        CRF_STEP(t + 3, 1, 0, pfD, wregD);
    }
    // tail: t = 509, 510, 511  (parity: final EA lands in ea[1])
    CRF_STEP(509, 0, 1, pfA, wregA);
    CRF_STEP(510, 1, 0, pfB, wregB);
    CRF_STEP(511, 0, 1, pfC, wregC);
#undef CRF_STEP

    // ---- final: logZ_b = ln2 * (S + log2(sum_k EA_last[k])) ----
    if (tid < 64) {
        unsigned u = *reinterpret_cast<const unsigned*>(&ea[1][tid * 4]);
        float s = __builtin_amdgcn_cvt_f32_fp8((int)u, 0)
                + __builtin_amdgcn_cvt_f32_fp8((int)u, 1)
                + __builtin_amdgcn_cvt_f32_fp8((int)u, 2)
                + __builtin_amdgcn_cvt_f32_fp8((int)u, 3);
        #pragma unroll
        for (int off = 32; off; off >>= 1) s += __shfl_xor(s, off);
        if (tid == 0) bout[blockIdx.x] = (S + log2_fast(s)) * LN2;
    }
}

__global__ void crf_reduce(const float* __restrict__ bout, float* __restrict__ out)
{
    const int tid = threadIdx.x;  // 128 threads
    float v = bout[tid];
    #pragma unroll
    for (int off = 32; off; off >>= 1) v += __shfl_xor(v, off);
    __shared__ float sred[2];
    if ((tid & 63) == 0) sred[tid >> 6] = v;
    __syncthreads();
    if (tid == 0) out[0] = sred[0] + sred[1];
}

extern "C" void kernel_launch(void* const* d_in, const int* in_sizes, int n_in,
                              void* d_out, int out_size, void* d_ws, size_t ws_size,
                              hipStream_t stream)
{
    const float* emis  = (const float*)d_in[0];
    const float* trans = (const float*)d_in[1];
    const int*   words = (const int*)d_in[2];
    float* out  = (float*)d_out;
    float* bout = (float*)d_ws;   // NWG floats of scratch

    crf_forward<<<NWG, 512, 0, stream>>>(emis, trans, words, bout);
    crf_reduce<<<1, NB, 0, stream>>>(bout, out);
}

// Round 17
// 292.974 us; speedup vs baseline: 1.1035x; 1.0540x over previous
//
#include <hip/hip_runtime.h>

#define NB 128
#define NT 512
#define NL 256
#define NWG NB           // one workgroup per batch

typedef float f32x4 __attribute__((ext_vector_type(4)));
typedef int   i32x8 __attribute__((ext_vector_type(8)));

#define EASTRIDE 272     // bytes per EA buffer (256 + 16 pad, 16B aligned)
#define GEXP 7           // a-priori per-step log2 growth estimate
#define E8M0_ONE 127     // e8m0 encoding of 1.0 for mfma_scale
#define INV_LN2 1.4426950408889634f
#define LN2 0.6931471805599453f

__device__ inline float log2_fast(float x) {
#if __has_builtin(__builtin_amdgcn_logf)
    return __builtin_amdgcn_logf(x);
#else
    return __log2f(x);
#endif
}
__device__ inline float exp2_fast(float x) {
#if __has_builtin(__builtin_amdgcn_exp2f)
    return __builtin_amdgcn_exp2f(x);
#else
    return exp2f(x);
#endif
}

// Barrier that waits only on LDS ops — prefetch global loads stay in flight.
__device__ inline void barrier_lds_only() {
    asm volatile("s_waitcnt lgkmcnt(0)" ::: "memory");
    __builtin_amdgcn_s_barrier();
    asm volatile("" ::: "memory");
}

// pack 4 f32 -> 4 fp8 e4m3 bytes (saturating)
__device__ inline unsigned pk_fp8x4(float a, float b, float c, float d) {
    int w = __builtin_amdgcn_cvt_pk_fp8_f32(a, b, 0, false);
    w     = __builtin_amdgcn_cvt_pk_fp8_f32(c, d, w, true);
    return (unsigned)w;
}

// One WG (512 thr = 8 waves, 2 waves/SIMD) per batch — round-13 kernel,
// the session's verified best (293 us, absmax 0.0).  Exp-space recurrence,
// damped power-of-2 normalization from a one-step-stale max, S accumulates
// exact integer exponents.  Structural floor analysis (r13-r16): step =
// barrier + ds_read + scale-MFMA chain + normalize tail ~= 1400 cy; four
// independent optimization directions (occupancy, VALU-issue, chain depth,
// reduce width) all land within ±10% of this floor.
// Layout (16x16x128, shape-determined): A row=lane&15, k=(lane>>4)*32+j;
// B col=lane&15 (batch dup), k=(lane>>4)*32+j; D col=lane&15, row=g*4+reg.
__global__ __launch_bounds__(512, 2) void crf_forward(
    const float* __restrict__ emis,
    const float* __restrict__ trans,
    const int*   __restrict__ words,
    float*       __restrict__ bout)
{
    const int tid = threadIdx.x;
    const int l   = tid & 63;
    const int wv  = tid >> 6;    // 0..7
    const int g   = l >> 4;      // 0..3
    const int b   = l & 15;

    __shared__ __align__(16) unsigned char ea[2][EASTRIDE]; // fp8 EA, dbuf
    __shared__ __align__(16) float pm[2][8];                // per-wave stale maxes
    __shared__ int wlds[NT];                                // staged word indices

    const int wrow = blockIdx.x * NT;

    // ---- stage word indices to LDS ----
    wlds[tid] = words[wrow + tid];

    // ---- A-fragments: exp(trans) rows wv*32 + T*16 + b, K=128 layout ----
    i32x8 afr[2][2];
    #pragma unroll
    for (int T = 0; T < 2; ++T) {
        const int row = wv * 32 + T * 16 + b;
        #pragma unroll
        for (int kt = 0; kt < 2; ++kt) {
            const float* src = trans + row * NL + kt * 128 + g * 32;
            i32x8 a;
            #pragma unroll
            for (int w = 0; w < 8; ++w) {
                float4 v = *reinterpret_cast<const float4*>(src + w * 4);
                a[w] = (int)pk_fp8x4(__expf(v.x), __expf(v.y),
                                     __expf(v.z), __expf(v.w));
            }
            afr[T][kt] = a;
        }
    }

    // ---- word pipeline (prologue direct; steady: wlds ds_read) ----
    const int w0 = words[wrow + 0];
    const int w1 = words[wrow + 1];
    const int w2 = words[wrow + 2];
    const int w3 = words[wrow + 3];
    const int w4 = words[wrow + 4];
    int wregA = words[wrow + 5];
    int wregB = words[wrow + 6];
    int wregC = words[wrow + 7];
    int wregD = words[wrow + 8];

    float S = 0.f;   // exponent accumulator (exact small ints, same in all lanes)

    // ---- t=0 : EA_0 = fp8(2^(e0*INV_LN2)), rows wv*32 + T*16 + g*4 + j ----
    {
        const float* e0 = emis + (size_t)w0 * NL + wv * 32 + g * 4;
        float pmax = 0.f;
        unsigned pk[2];
        #pragma unroll
        for (int T = 0; T < 2; ++T) {
            f32x4 v = *reinterpret_cast<const f32x4*>(e0 + T * 16);
            float p0 = exp2_fast(v[0] * INV_LN2);
            float p1 = exp2_fast(v[1] * INV_LN2);
            float p2 = exp2_fast(v[2] * INV_LN2);
            float p3 = exp2_fast(v[3] * INV_LN2);
            pmax = fmaxf(pmax, fmaxf(fmaxf(p0, p1), fmaxf(p2, p3)));
            pk[T] = pk_fp8x4(p0, p1, p2, p3);
        }
        pmax = fmaxf(pmax, __shfl_xor(pmax, 16));
        pmax = fmaxf(pmax, __shfl_xor(pmax, 32));
        if (l == 0) pm[0][wv] = pmax;
        if (b == 0) {
            *reinterpret_cast<unsigned*>(&ea[0][wv * 32 + g * 4])      = pk[0];
            *reinterpret_cast<unsigned*>(&ea[0][wv * 32 + 16 + g * 4]) = pk[1];
        }
    }
    f32x4 pfA[2], pfB[2], pfC[2], pfD[2];
    {
        const float* p;
        p = emis + (size_t)w1 * NL + wv * 32 + g * 4;
        pfA[0] = *(const f32x4*)p; pfA[1] = *(const f32x4*)(p + 16);
        p = emis + (size_t)w2 * NL + wv * 32 + g * 4;
        pfB[0] = *(const f32x4*)p; pfB[1] = *(const f32x4*)(p + 16);
        p = emis + (size_t)w3 * NL + wv * 32 + g * 4;
        pfC[0] = *(const f32x4*)p; pfC[1] = *(const f32x4*)(p + 16);
        p = emis + (size_t)w4 * NL + wv * 32 + g * 4;
        pfD[0] = *(const f32x4*)p; pfD[1] = *(const f32x4*)(p + 16);
    }
    barrier_lds_only();

#define CRF_STEP(t, RD, WR, PF, WREG)                                           \
    {                                                                           \
        /* B-frags: natural contiguous, broadcast b128 reads */                 \
        i32x8 bq0 = *reinterpret_cast<const i32x8*>(&ea[RD][g * 32]);           \
        i32x8 bq1 = *reinterpret_cast<const i32x8*>(&ea[RD][128 + g * 32]);     \
        f32x4 pm0 = *reinterpret_cast<const f32x4*>(&pm[RD][0]);                \
        f32x4 pm1 = *reinterpret_cast<const f32x4*>(&pm[RD][4]);                \
        float gm  = fmaxf(fmaxf(fmaxf(pm0[0], pm0[1]), fmaxf(pm0[2], pm0[3])),  \
                          fmaxf(fmaxf(pm1[0], pm1[1]), fmaxf(pm1[2], pm1[3]))); \
        int   kb  = (int)(__builtin_bit_cast(unsigned, gm) >> 23) - (127 - GEXP);\
        S += (float)kb;                                                         \
        float kbf = (float)kb;                                                  \
        f32x4 eC[2] = { PF[0], PF[1] };                                         \
        if ((t) + 4 < NT) {                                                     \
            const float* ep = emis + (size_t)WREG * NL + wv * 32 + g * 4;       \
            PF[0] = *(const f32x4*)ep;  PF[1] = *(const f32x4*)(ep + 16);       \
        }                                                                       \
        if ((t) + 8 < NT) WREG = wlds[(t) + 8];                                 \
        /* ex hides under lgkm/MFMA wait */                                     \
        f32x4 ex[2];                                                            \
        _Pragma("unroll")                                                       \
        for (int T = 0; T < 2; ++T) {                                           \
            ex[T][0] = exp2_fast(fmaf(eC[T][0], INV_LN2, -kbf));                \
            ex[T][1] = exp2_fast(fmaf(eC[T][1], INV_LN2, -kbf));                \
            ex[T][2] = exp2_fast(fmaf(eC[T][2], INV_LN2, -kbf));                \
            ex[T][3] = exp2_fast(fmaf(eC[T][3], INV_LN2, -kbf));                \
        }                                                                       \
        /* 2 independent depth-2 scale-MFMA chains (K=128 each) */              \
        f32x4 sA[2];                                                            \
        _Pragma("unroll")                                                       \
        for (int T = 0; T < 2; ++T) {                                           \
            f32x4 z = {0.f, 0.f, 0.f, 0.f};                                     \
            z = __builtin_amdgcn_mfma_scale_f32_16x16x128_f8f6f4(               \
                    afr[T][0], bq0, z, 0, 0, 0, E8M0_ONE, 0, E8M0_ONE);         \
            z = __builtin_amdgcn_mfma_scale_f32_16x16x128_f8f6f4(               \
                    afr[T][1], bq1, z, 0, 0, 0, E8M0_ONE, 0, E8M0_ONE);         \
            sA[T] = z;                                                          \
        }                                                                       \
        float pmax = 0.f;                                                       \
        unsigned pk[2];                                                         \
        _Pragma("unroll")                                                       \
        for (int T = 0; T < 2; ++T) {                                           \
            f32x4 wv4 = sA[T] * ex[T];                                          \
            pmax = fmaxf(pmax, fmaxf(fmaxf(wv4[0], wv4[1]),                     \
                                     fmaxf(wv4[2], wv4[3])));                   \
            pk[T] = pk_fp8x4(wv4[0], wv4[1], wv4[2], wv4[3]);                   \
        }                                                                       \
        pmax = fmaxf(pmax, __shfl_xor(pmax, 16));                               \
        pmax = fmaxf(pmax, __shfl_xor(pmax, 32));                               \
        if (l == 0) pm[WR][wv] = pmax;                                          \
        if (b == 0) {                                                           \
            *reinterpret_cast<unsigned*>(&ea[WR][wv * 32 + g * 4])      = pk[0];\
            *reinterpret_cast<unsigned*>(&ea[WR][wv * 32 + 16 + g * 4]) = pk[1];\
        }                                                                       \
        barrier_lds_only();                                                     \
    }

    int t = 1;
    for (; t + 3 < NT; t += 4) {
        CRF_STEP(t,     0, 1, pfA, wregA);
        CRF_STEP(t + 1, 1, 0, pfB, wregB);
        CRF_STEP(t + 2, 0, 1, pfC, wregC);
        CRF_STEP(t + 3, 1, 0, pfD, wregD);
    }
    // tail: t = 509, 510, 511  (parity: final EA lands in ea[1])
    CRF_STEP(509, 0, 1, pfA, wregA);
    CRF_STEP(510, 1, 0, pfB, wregB);
    CRF_STEP(511, 0, 1, pfC, wregC);
#undef CRF_STEP

    // ---- final: logZ_b = ln2 * (S + log2(sum_k EA_last[k])) ----
    if (tid < 64) {
        unsigned u = *reinterpret_cast<const unsigned*>(&ea[1][tid * 4]);
        float s = __builtin_amdgcn_cvt_f32_fp8((int)u, 0)
                + __builtin_amdgcn_cvt_f32_fp8((int)u, 1)
                + __builtin_amdgcn_cvt_f32_fp8((int)u, 2)
                + __builtin_amdgcn_cvt_f32_fp8((int)u, 3);
        #pragma unroll
        for (int off = 32; off; off >>= 1) s += __shfl_xor(s, off);
        if (tid == 0) bout[blockIdx.x] = (S + log2_fast(s)) * LN2;
    }
}

__global__ void crf_reduce(const float* __restrict__ bout, float* __restrict__ out)
{
    const int tid = threadIdx.x;  // 128 threads
    float v = bout[tid];
    #pragma unroll
    for (int off = 32; off; off >>= 1) v += __shfl_xor(v, off);
    __shared__ float sred[2];
    if ((tid & 63) == 0) sred[tid >> 6] = v;
    __syncthreads();
    if (tid == 0) out[0] = sred[0] + sred[1];
}

extern "C" void kernel_launch(void* const* d_in, const int* in_sizes, int n_in,
                              void* d_out, int out_size, void* d_ws, size_t ws_size,
                              hipStream_t stream)
{
    const float* emis  = (const float*)d_in[0];
    const float* trans = (const float*)d_in[1];
    const int*   words = (const int*)d_in[2];
    float* out  = (float*)d_out;
    float* bout = (float*)d_ws;   // NWG floats of scratch

    crf_forward<<<NWG, 512, 0, stream>>>(emis, trans, words, bout);
    crf_reduce<<<1, NB, 0, stream>>>(bout, out);
}